// Round 1
// baseline (6049.960 us; speedup 1.0000x reference)
//
#include <hip/hip_runtime.h>

#define TT 2048
#define BATCH 512
#define DIMK 25
#define LAYERS 10
#define NC 7

__device__ __forceinline__ float sigm(float z) {
  // 1 / (1 + exp(-z))
  return __builtin_amdgcn_rcpf(1.0f + __expf(-z));
}

__launch_bounds__(512, 2)
__global__ void lstm_fused(const float* __restrict__ x,
                           const float* __restrict__ h0,
                           const float* __restrict__ c0,
                           const float* __restrict__ Wih,
                           const float* __restrict__ Whh,
                           const float* __restrict__ bias,
                           const float* __restrict__ fcw,
                           const float* __restrict__ fcb,
                           float* __restrict__ out) {
  // buf[b][slot][.] : slot 0 = x(t), slot l+1 = h_l output. Padded to 32 floats
  // (128B) so float4 LDS reads are 16B aligned.
  __shared__ __align__(16) float buf[2][LAYERS + 1][32];
  __shared__ __align__(16) float gbuf[2][LAYERS][100];  // only f (25..49) and o (75..99) rows used
  __shared__ __align__(16) float h9p[2][2][32];         // parity-buffered layer-9 h for FC
  __shared__ float eb[2][8];                            // FC exp staging (wave-7 local)

  const int tid = threadIdx.x;
  const int blk = blockIdx.x;
  const int l = tid / 50;          // 0..9 for compute threads; 10 for tid>=500
  const int u = tid % 50;
  const bool comp = (tid < 500);
  const int lcl = (l > 9) ? 9 : l; // clamped, for pointer setup only
  const int b0 = 2 * blk;          // global batch base for this block

  // Resident per-thread weights: gate rows r1=u (i or f), r2=u+50 (g or o)
  float wih1[DIMK], wih2[DIMK], whh1[DIMK], whh2[DIMK];
  float bias1 = 0.f, bias2 = 0.f;
  float cA = 0.f, cB = 0.f;        // cell state for unit u (u<25), both batch elems
  float fw[DIMK];                  // FC weights (FC threads only)
  float fb0 = 0.f;

  const bool isfc = comp && (l == 9) && (u >= 25) && (u < 39);
  const int fci = u - 25;          // 0..13
  const int fcbatch = fci / 7;     // 0..1
  const int fccls = fci % 7;       // 0..6

  if (comp) {
    const int r1 = u, r2 = u + 50;
    const float* wi1 = Wih + (l * 100 + r1) * DIMK;
    const float* wi2 = Wih + (l * 100 + r2) * DIMK;
    const float* wh1 = Whh + (l * 100 + r1) * DIMK;
    const float* wh2 = Whh + (l * 100 + r2) * DIMK;
#pragma unroll
    for (int k = 0; k < DIMK; ++k) {
      wih1[k] = wi1[k]; wih2[k] = wi2[k];
      whh1[k] = wh1[k]; whh2[k] = wh2[k];
    }
    bias1 = bias[l * 100 + r1];
    bias2 = bias[l * 100 + r2];
    if (u < 25) {
      cA = c0[(l * BATCH + b0 + 0) * DIMK + u];
      cB = c0[(l * BATCH + b0 + 1) * DIMK + u];
      buf[0][l + 1][u] = h0[(l * BATCH + b0 + 0) * DIMK + u];
      buf[1][l + 1][u] = h0[(l * BATCH + b0 + 1) * DIMK + u];
    }
    if (l == 0 && u >= 25) {
      // preload x(t=0): 50 contiguous floats (batch b0, b0+1)
      const int i = u - 25;
      const float* xp = x + (size_t)b0 * DIMK;  // t=0
      const int j0 = 2 * i, j1 = 2 * i + 1;
      buf[j0 / 25][0][j0 % 25] = xp[j0];
      buf[j1 / 25][0][j1 % 25] = xp[j1];
    }
    if (isfc) {
#pragma unroll
      for (int k = 0; k < DIMK; ++k) fw[k] = fcw[fccls * DIMK + k];
      fb0 = fcb[fccls];
    }
  }
  __syncthreads();

  // r2 activation: tanh for u<25 (g gate), sigmoid for u>=25 (o gate).
  // tanh(z) = 2*sigm(2z) - 1  -> branchless via scale s2.
  const float s2 = (u < 25) ? 2.0f : 1.0f;
  const float s2m1 = s2 - 1.0f;

  const float* inpA = &buf[0][lcl][0];
  float* ownA = &buf[0][lcl + 1][0];
  const float* inpB = &buf[1][lcl][0];
  float* ownB = &buf[1][lcl + 1][0];

  float g1A = 0.f, g2A = 0.f, g1B = 0.f, g2B = 0.f;
  float xpre0 = 0.f, xpre1 = 0.f;

  for (int s = 0; s < TT + LAYERS; ++s) {
    const int t = s - l;
    const bool act = comp && ((unsigned)t < (unsigned)TT);

    // Issue x(t+1) prefetch early so global latency hides under phase 1.
    if (comp && l == 0 && u >= 25 && (s + 1) < TT) {
      const int i = u - 25;
      const float* xp = x + ((size_t)(s + 1) * BATCH + b0) * DIMK;
      xpre0 = xp[2 * i];
      xpre1 = xp[2 * i + 1];
    }

    if (act) {
      // ---- phase 1: gate preactivations (2 gates x 2 batch = 4 dots of 50)
      float ai1A = 0.f, ai2A = 0.f, ah1A = 0.f, ah2A = 0.f;
      float ai1B = 0.f, ai2B = 0.f, ah1B = 0.f, ah2B = 0.f;
#pragma unroll
      for (int kk = 0; kk < 24; kk += 4) {
        const float4 viA = *(const float4*)(inpA + kk);
        const float4 vhA = *(const float4*)(ownA + kk);
        const float4 viB = *(const float4*)(inpB + kk);
        const float4 vhB = *(const float4*)(ownB + kk);
        ai1A += wih1[kk+0]*viA.x; ai1A += wih1[kk+1]*viA.y; ai1A += wih1[kk+2]*viA.z; ai1A += wih1[kk+3]*viA.w;
        ai2A += wih2[kk+0]*viA.x; ai2A += wih2[kk+1]*viA.y; ai2A += wih2[kk+2]*viA.z; ai2A += wih2[kk+3]*viA.w;
        ah1A += whh1[kk+0]*vhA.x; ah1A += whh1[kk+1]*vhA.y; ah1A += whh1[kk+2]*vhA.z; ah1A += whh1[kk+3]*vhA.w;
        ah2A += whh2[kk+0]*vhA.x; ah2A += whh2[kk+1]*vhA.y; ah2A += whh2[kk+2]*vhA.z; ah2A += whh2[kk+3]*vhA.w;
        ai1B += wih1[kk+0]*viB.x; ai1B += wih1[kk+1]*viB.y; ai1B += wih1[kk+2]*viB.z; ai1B += wih1[kk+3]*viB.w;
        ai2B += wih2[kk+0]*viB.x; ai2B += wih2[kk+1]*viB.y; ai2B += wih2[kk+2]*viB.z; ai2B += wih2[kk+3]*viB.w;
        ah1B += whh1[kk+0]*vhB.x; ah1B += whh1[kk+1]*vhB.y; ah1B += whh1[kk+2]*vhB.z; ah1B += whh1[kk+3]*vhB.w;
        ah2B += whh2[kk+0]*vhB.x; ah2B += whh2[kk+1]*vhB.y; ah2B += whh2[kk+2]*vhB.z; ah2B += whh2[kk+3]*vhB.w;
      }
      const float viA24 = inpA[24], vhA24 = ownA[24];
      const float viB24 = inpB[24], vhB24 = ownB[24];
      const float a1A = bias1 + ai1A + ah1A + wih1[24]*viA24 + whh1[24]*vhA24;
      const float a2A = bias2 + ai2A + ah2A + wih2[24]*viA24 + whh2[24]*vhA24;
      const float a1B = bias1 + ai1B + ah1B + wih1[24]*viB24 + whh1[24]*vhB24;
      const float a2B = bias2 + ai2B + ah2B + wih2[24]*viB24 + whh2[24]*vhB24;

      g1A = sigm(a1A);                      // i (u<25) or f (u>=25)
      g2A = s2 * sigm(s2 * a2A) - s2m1;     // tanh->g (u<25) or sigmoid->o
      g1B = sigm(a1B);
      g2B = s2 * sigm(s2 * a2B) - s2m1;

      if (u >= 25) {                        // publish f and o; i,g stay in regs
        gbuf[0][l][u]      = g1A;
        gbuf[0][l][u + 50] = g2A;
        gbuf[1][l][u]      = g1B;
        gbuf[1][l][u + 50] = g2B;
      }
    }
    __syncthreads();

    // ---- phase 2: cell/hidden update on unit threads (u<25)
    if (act && u < 25) {
      const float fA = gbuf[0][l][u + 25], oA = gbuf[0][l][u + 75];
      const float fB = gbuf[1][l][u + 25], oB = gbuf[1][l][u + 75];
      cA = fA * cA + g1A * g2A;             // f*c + i*g
      cB = fB * cB + g1B * g2B;
      const float tA = 2.0f * sigm(2.0f * cA) - 1.0f;  // tanh(c)
      const float tB = 2.0f * sigm(2.0f * cB) - 1.0f;
      const float hA = oA * tA;
      const float hB = oB * tB;
      ownA[u] = hA;
      ownB[u] = hB;
      if (l == 9) {
        h9p[s & 1][0][u] = hA;
        h9p[s & 1][1][u] = hB;
      }
    }
    // x prefetch commit (layer-0 f/o threads, idle in phase 2)
    if (comp && l == 0 && u >= 25 && (s + 1) < TT) {
      const int i = u - 25;
      const int j0 = 2 * i, j1 = 2 * i + 1;
      buf[j0 / 25][0][j0 % 25] = xpre0;
      buf[j1 / 25][0][j1 % 25] = xpre1;
    }
    // FC + softmax on layer-9 f/o threads (idle in phase 2), one step behind h9
    if (isfc) {
      const int tf = s - 10;
      if ((unsigned)tf < (unsigned)TT) {
        const float* hp = &h9p[(s + 1) & 1][fcbatch][0];  // parity of step s-1
        float acc = fb0;
#pragma unroll
        for (int kk = 0; kk < 24; kk += 4) {
          const float4 v = *(const float4*)(hp + kk);
          acc += fw[kk+0]*v.x; acc += fw[kk+1]*v.y; acc += fw[kk+2]*v.z; acc += fw[kk+3]*v.w;
        }
        acc += fw[24] * hp[24];
        // |logit| <= ~5.2, no max-subtraction needed
        const float e = __expf(acc);
        eb[fcbatch][fccls] = e;   // all 14 FC lanes are in wave 7: in-order LDS
        const float ssum = eb[fcbatch][0] + eb[fcbatch][1] + eb[fcbatch][2] +
                           eb[fcbatch][3] + eb[fcbatch][4] + eb[fcbatch][5] +
                           eb[fcbatch][6];
        out[((size_t)tf * BATCH + b0 + fcbatch) * NC + fccls] =
            e * __builtin_amdgcn_rcpf(ssum);
      }
    }
    __syncthreads();
  }
}

extern "C" void kernel_launch(void* const* d_in, const int* in_sizes, int n_in,
                              void* d_out, int out_size, void* d_ws, size_t ws_size,
                              hipStream_t stream) {
  const float* x   = (const float*)d_in[0];
  const float* h0  = (const float*)d_in[1];
  const float* c0  = (const float*)d_in[2];
  const float* Wih = (const float*)d_in[3];
  const float* Whh = (const float*)d_in[4];
  const float* b   = (const float*)d_in[5];
  const float* fcw = (const float*)d_in[6];
  const float* fcb = (const float*)d_in[7];
  float* out = (float*)d_out;

  lstm_fused<<<dim3(256), dim3(512), 0, stream>>>(x, h0, c0, Wih, Whh, b, fcw,
                                                  fcb, out);
}